// Round 20
// baseline (263.417 us; speedup 1.0000x reference)
//
#include <hip/hip_runtime.h>
#include <hip/hip_bf16.h>

#define N_NODES 50000
#define N_EDGES 800000
#define D_IN    512
#define D_OUT   256
#define NBLK_SCAN ((N_NODES + 1023) / 1024)   // 49
#define GEMM_NWG (((N_NODES + 127) / 128) * 2)  // 782
#define GEMM_Q   (GEMM_NWG / 8)                  // 97
#define GEMM_R   (GEMM_NWG % 8)                  // 6
#define GATH_CHUNKS ((N_NODES + 63) / 64)        // 782

typedef short s8v  __attribute__((ext_vector_type(8)));
typedef float f32x4 __attribute__((ext_vector_type(4)));

__device__ __forceinline__ unsigned short bf16b(float f) {
    __hip_bfloat16 h = __float2bfloat16(f);
    return *reinterpret_cast<unsigned short*>(&h);
}
__device__ __forceinline__ float bflo(unsigned u) { return __uint_as_float(u << 16); }
__device__ __forceinline__ float bfhi(unsigned u) { return __uint_as_float(u & 0xffff0000u); }

__device__ __forceinline__ int wave_incl_scan(int v, int lane) {
    #pragma unroll
    for (int d = 1; d < 64; d <<= 1) {
        int u = __shfl_up(v, d, 64);
        if (lane >= d) v += u;
    }
    return v;
}

// ============ W transpose + bf16 convert; also zeroes cnt4 (saves a memset) ===
__global__ void k_wt(const float* __restrict__ W, unsigned short* __restrict__ Wt,
                     int* __restrict__ cnt4) {
    int k = blockIdx.x;      // 512
    int n = threadIdx.x;     // 256
    Wt[(size_t)n * D_IN + k] = bf16b(W[(size_t)k * D_OUT + n]);
    int t = (blockIdx.x * 256 + threadIdx.x) * 2;     // 262144 slots >= 200000
    if (t < 4 * N_NODES) {
        cnt4[t] = 0;
        if (t + 1 < 4 * N_NODES) cnt4[t + 1] = 0;
    }
}

// ============ CSR build (4-way replicated counters) ============

__global__ void k_count(const int* __restrict__ col, int* __restrict__ cnt4) {
    int i = (blockIdx.x * 256 + threadIdx.x) * 2;
    if (i < N_EDGES) {                            // N_EDGES even; i even
        int2 c = *(const int2*)&col[i];
        atomicAdd(&cnt4[(i & 3) * N_NODES + c.x], 1);
        atomicAdd(&cnt4[((i + 1) & 3) * N_NODES + c.y], 1);
    }
}

__launch_bounds__(256)
__global__ void k_scan1(const int* __restrict__ cnt4, int* __restrict__ bsum) {
    const int t = threadIdx.x, b = blockIdx.x;
    const int idx = b * 1024 + t * 4;
    int s = 0;
    if (idx < N_NODES) {
        #pragma unroll
        for (int q = 0; q < 4; ++q) {
            int4 v = *(const int4*)&cnt4[q * N_NODES + idx];
            s += (v.x + v.y) + (v.z + v.w);
        }
    }
    #pragma unroll
    for (int d = 1; d < 64; d <<= 1) s += __shfl_xor(s, d, 64);
    __shared__ int ws[4];
    if ((t & 63) == 0) ws[t >> 6] = s;
    __syncthreads();
    if (t == 0) bsum[b] = ws[0] + ws[1] + ws[2] + ws[3];
}

// in-block exclusive scan + self-computed block offset; emits row_ptr, dinv,
// and EXACT per-replica cursor bases cursor4[q*N+c] = row_ptr[c]+prefix_q
__launch_bounds__(256)
__global__ void k_scan3(const int* __restrict__ cnt4, const int* __restrict__ bsum,
                        int* __restrict__ row_ptr, float* __restrict__ dinv,
                        int* __restrict__ cursor4) {
    const int t = threadIdx.x, b = blockIdx.x;
    const int lane = t & 63, wv = t >> 6;
    const int idx = b * 1024 + t * 4;
    int4 vq[4];
    int4 tot = make_int4(0, 0, 0, 0);
    if (idx < N_NODES) {
        #pragma unroll
        for (int q = 0; q < 4; ++q) {
            vq[q] = *(const int4*)&cnt4[q * N_NODES + idx];
            tot.x += vq[q].x; tot.y += vq[q].y;
            tot.z += vq[q].z; tot.w += vq[q].w;
        }
    } else {
        #pragma unroll
        for (int q = 0; q < 4; ++q) vq[q] = make_int4(0, 0, 0, 0);
    }
    int s = (tot.x + tot.y) + (tot.z + tot.w);
    int isc = wave_incl_scan(s, lane);
    __shared__ int wsum[4];
    __shared__ int s_boff;
    if (lane == 63) wsum[wv] = isc;
    if (t < 64) {                                  // wave 0: sum of bsum[0..b)
        int u = (t < b) ? bsum[t] : 0;             // b <= 48 < 64
        #pragma unroll
        for (int d = 1; d < 64; d <<= 1) u += __shfl_xor(u, d, 64);
        if (t == 0) s_boff = u;
    }
    __syncthreads();
    int off = s_boff;
    #pragma unroll
    for (int i = 0; i < 4; ++i)
        if (i < wv) off += wsum[i];
    int p0 = off + isc - s;
    int p1 = p0 + tot.x;
    int p2 = p1 + tot.y;
    int p3 = p2 + tot.z;
    if (idx < N_NODES) {
        row_ptr[idx + 0] = p0; dinv[idx + 0] = rsqrtf(1.f + (float)tot.x);
        row_ptr[idx + 1] = p1; dinv[idx + 1] = rsqrtf(1.f + (float)tot.y);
        row_ptr[idx + 2] = p2; dinv[idx + 2] = rsqrtf(1.f + (float)tot.z);
        row_ptr[idx + 3] = p3; dinv[idx + 3] = rsqrtf(1.f + (float)tot.w);
        int4 run = make_int4(p0, p1, p2, p3);
        #pragma unroll
        for (int q = 0; q < 4; ++q) {
            *(int4*)&cursor4[q * N_NODES + idx] = run;
            run.x += vq[q].x; run.y += vq[q].y;
            run.z += vq[q].z; run.w += vq[q].w;
        }
    }
    if (b == 0 && t == 0) row_ptr[N_NODES] = N_EDGES;
}

__global__ void k_fill(const int* __restrict__ row, const int* __restrict__ col,
                       int* __restrict__ cursor4, int* __restrict__ csr_src) {
    int i = (blockIdx.x * 256 + threadIdx.x) * 2;
    if (i < N_EDGES) {
        int2 c = *(const int2*)&col[i];
        int2 r = *(const int2*)&row[i];
        int p0 = atomicAdd(&cursor4[(i & 3) * N_NODES + c.x], 1);
        csr_src[p0] = r.x;
        int p1 = atomicAdd(&cursor4[((i + 1) & 3) * N_NODES + c.y], 1);
        csr_src[p1] = r.y;
    }
}

// ============ MFMA GEMM: yb_blk = bf16(dinv[r] * (x @ W)), COLUMN-BLOCKED ====
// R4-R19 synthesis: gemm time tracks global_load_lds BYTES across 6 structures
// (~16 B/cy/CU DMA fill rate = the wall). THIS version bypasses the DMA engine:
// reg-staged (global->VGPR->ds_write), single 24KB buffer, BK=32, with T14
// issue-early/write-late (loads for tile k+2 issued right after writing k+1,
// riding under COMPUTE(k+1)). RAW s_barrier + explicit lgkmcnt (NOT
// __syncthreads: its vmcnt(0) drain would kill the in-flight register loads).
// BK=32 keeps staging regs at 24/thread (R5's spill was 48 at BK=64);
// (256,2) caps VGPR at 256 -> no spill (tripwire: WRITE_SIZE == 25.6MB).
__launch_bounds__(256, 2)
__global__ void k_gemm(const float* __restrict__ A,            // [N_NODES,512] fp32
                       const unsigned short* __restrict__ Wt,  // [256,512] bf16
                       const float* __restrict__ dinv,
                       unsigned short* __restrict__ yb)        // [8][N_NODES][32] bf16
{
    __shared__ __align__(16) float          As[128 * 32];   // 16 KB
    __shared__ __align__(16) unsigned short Bs[128 * 32];   // 8 KB

    // bijective XCD swizzle (m204)
    int orig = blockIdx.x;
    int xcd = orig % 8, pos = orig / 8;
    int wg = (xcd < GEMM_R) ? xcd * (GEMM_Q + 1) + pos
                            : GEMM_R * (GEMM_Q + 1) + (xcd - GEMM_R) * GEMM_Q + pos;
    const int nt = wg & 1;
    const int mt = wg >> 1;
    const int m0 = mt * 128;
    const int n0 = nt * 128;

    const int t  = threadIdx.x;
    const int w  = t >> 6;
    const int l  = t & 63;
    const int wm = (w >> 1) * 64;
    const int wn = (w & 1) * 64;
    const int lr = l & 15;
    const int lk = l >> 4;

    // ---- staging maps (thread t) ----
    // A: rows i*32+(t>>3) (i=0..3), 16B chunk t&7 of the K=32 span.
    //    LDS stored slot = (t&7) ^ (row&7), row&7 == (t>>3)&7.
    const float* agp[4];
    unsigned     awb[4];
    #pragma unroll
    for (int i = 0; i < 4; ++i) {
        int rl = i * 32 + (t >> 3);
        int rg = m0 + rl;
        if (rg >= N_NODES) rg = 0;               // tail clamp; outputs guarded
        agp[i] = A + (size_t)rg * D_IN + (t & 7) * 4;
        awb[i] = rl * 128 + (((t & 7) ^ ((t >> 3) & 7)) << 4);
    }
    // B: rows i*64+(t>>2) (i=0..1), 16B chunk t&3.
    //    stored slot = (t&3) ^ ((row>>1)&3), (row>>1)&3 == (t>>3)&3.
    const unsigned short* bgp[2];
    unsigned              bwb[2];
    #pragma unroll
    for (int i = 0; i < 2; ++i) {
        int rl = i * 64 + (t >> 2);
        bgp[i] = Wt + (size_t)(n0 + rl) * D_IN + (t & 3) * 8;
        bwb[i] = rl * 64 + (((t & 3) ^ ((t >> 3) & 3)) << 4);
    }

    float4 ar[4];
    uint4  br[2];

    #define LOADR(kk)                                                \
        do {                                                         \
            _Pragma("unroll")                                        \
            for (int i = 0; i < 4; ++i)                              \
                ar[i] = *(const float4*)(agp[i] + (kk));             \
            _Pragma("unroll")                                        \
            for (int i = 0; i < 2; ++i)                              \
                br[i] = *(const uint4*)(bgp[i] + (kk));              \
        } while (0)

    #define DSW()                                                    \
        do {                                                         \
            _Pragma("unroll")                                        \
            for (int i = 0; i < 4; ++i)                              \
                *(float4*)((char*)As + awb[i]) = ar[i];              \
            _Pragma("unroll")                                        \
            for (int i = 0; i < 2; ++i)                              \
                *(uint4*)((char*)Bs + bwb[i]) = br[i];               \
        } while (0)

    #define PUBLISH()                                                \
        do {                                                         \
            asm volatile("s_waitcnt lgkmcnt(0)" ::: "memory");       \
            __builtin_amdgcn_sched_barrier(0);                       \
            __builtin_amdgcn_s_barrier();                            \
        } while (0)

    #define COMPUTE()                                                            \
        do {                                                                     \
            s8v af[4], bfr[4];                                                   \
            _Pragma("unroll")                                                    \
            for (int f = 0; f < 4; ++f) {                                        \
                int row = wm + f * 16 + lr;            /* row&7 == lr&7 */       \
                int s0  = (2 * lk) ^ (lr & 7);                                   \
                const char* pr = (const char*)As + row * 128;                    \
                float4 x0 = *(const float4*)(pr + s0 * 16);                      \
                float4 x1 = *(const float4*)(pr + (s0 ^ 1) * 16);                \
                union { s8v v; unsigned short h[8]; } u;                         \
                u.h[0] = bf16b(x0.x); u.h[1] = bf16b(x0.y);                      \
                u.h[2] = bf16b(x0.z); u.h[3] = bf16b(x0.w);                      \
                u.h[4] = bf16b(x1.x); u.h[5] = bf16b(x1.y);                      \
                u.h[6] = bf16b(x1.z); u.h[7] = bf16b(x1.w);                      \
                af[f] = u.v;                                                     \
            }                                                                    \
            _Pragma("unroll")                                                    \
            for (int f = 0; f < 4; ++f) {                                        \
                int row = wn + f * 16 + lr;        /* (row>>1)&3 == (lr>>1)&3 */ \
                int s   = lk ^ ((lr >> 1) & 3);                                  \
                bfr[f] = *(const s8v*)((const char*)Bs + row * 64 + s * 16);     \
            }                                                                    \
            _Pragma("unroll")                                                    \
            for (int fm = 0; fm < 4; ++fm)                                       \
                _Pragma("unroll")                                                \
                for (int fn = 0; fn < 4; ++fn)                                   \
                    acc[fm][fn] = __builtin_amdgcn_mfma_f32_16x16x32_bf16(       \
                        af[fm], bfr[fn], acc[fm][fn], 0, 0, 0);                  \
        } while (0)

    f32x4 acc[4][4] = {};

    // prologue: stage tile 0, start loads for tile 1
    LOADR(0);
    DSW();
    LOADR(32);
    PUBLISH();                                   // tile 0 visible

    #pragma unroll 1
    for (int tk = 0; tk < 15; ++tk) {
        COMPUTE();                               // tile tk (reads fully consumed)
        __builtin_amdgcn_s_barrier();            // all waves done reading
        DSW();                                   // write tile tk+1 (regs ready)
        if (tk < 14) LOADR((tk + 2) * 32);       // issue tile tk+2 loads NOW
        PUBLISH();                               // tile tk+1 visible
    }
    COMPUTE();                                   // tile 15

    #undef LOADR
    #undef DSW
    #undef PUBLISH
    #undef COMPUTE

    #pragma unroll
    for (int fm = 0; fm < 4; ++fm) {
        #pragma unroll
        for (int j = 0; j < 4; ++j) {
            int row = m0 + wm + fm * 16 + lk * 4 + j;
            if (row < N_NODES) {
                float s = dinv[row];
                #pragma unroll
                for (int fn = 0; fn < 4; ++fn) {
                    int col = n0 + wn + fn * 16 + lr;
                    size_t off = (size_t)(col >> 5) * (N_NODES * 32)
                               + (size_t)row * 32 + (col & 31);
                    yb[off] = bf16b(acc[fm][fn][j] * s);
                }
            }
        }
    }
}

// ============ gather (column-partitioned) — EXACT round-16 kernel (best:
// 61.2us, FETCH 60MB). slice = blockIdx%8 keeps each XCD in its 3.2MB
// L2-resident column slice. 4-lane groups, group = one target, lane owns one
// 16B col-slot; NO cross-lane reduction. Rounds of 4 edges in flight.
__device__ __forceinline__ void add8(float* acc, uint4 q) {
    unsigned x;
    x = q.x; acc[0] += bflo(x); acc[1] += bfhi(x);
    x = q.y; acc[2] += bflo(x); acc[3] += bfhi(x);
    x = q.z; acc[4] += bflo(x); acc[5] += bfhi(x);
    x = q.w; acc[6] += bflo(x); acc[7] += bfhi(x);
}

__launch_bounds__(256)
__global__ void k_gather(const int* __restrict__ row_ptr, const int* __restrict__ csr_src,
                         const unsigned short* __restrict__ yb,   // [8][N_NODES][32]
                         const float* __restrict__ dinv,
                         const float* __restrict__ bias, float* __restrict__ out)
{
    const int s     = blockIdx.x & 7;          // slice -> XCD (dispatch %8)
    const int chunk = blockIdx.x >> 3;
    const int g     = threadIdx.x >> 2;        // group 0..63 = target
    const int cs    = threadIdx.x & 3;         // 16B col-slot within slice
    const int c     = chunk * 64 + g;
    if (c >= N_NODES) return;

    const uint4* t4 = (const uint4*)(yb + (size_t)s * N_NODES * 32);  // 4 uint4/node

    float acc[8] = {0.f,0.f,0.f,0.f,0.f,0.f,0.f,0.f};

    const int e0 = row_ptr[c];
    const int e1 = row_ptr[c + 1];
    for (int i = e0; i < e1; i += 4) {
        int idx[4];
        #pragma unroll
        for (int j = 0; j < 4; ++j) {
            int p = i + j;
            idx[j] = csr_src[p < e1 ? p : e1 - 1];   // clamp: L1-hot re-read
        }
        uint4 v[4];
        #pragma unroll
        for (int j = 0; j < 4; ++j) v[j] = t4[(size_t)idx[j] * 4 + cs];
        #pragma unroll
        for (int j = 0; j < 4; ++j)
            if (i + j < e1) add8(acc, v[j]);         // group-uniform predicate
    }

    add8(acc, t4[(size_t)c * 4 + cs]);               // self-loop term

    const float sc = dinv[c];
    const int colb = s * 32 + cs * 8;
    float4 b0 = *(const float4*)&bias[colb];
    float4 b1 = *(const float4*)&bias[colb + 4];
    float4 o0, o1;
    o0.x = fmaxf(fmaf(acc[0], sc, b0.x), 0.f);
    o0.y = fmaxf(fmaf(acc[1], sc, b0.y), 0.f);
    o0.z = fmaxf(fmaf(acc[2], sc, b0.z), 0.f);
    o0.w = fmaxf(fmaf(acc[3], sc, b0.w), 0.f);
    o1.x = fmaxf(fmaf(acc[4], sc, b1.x), 0.f);
    o1.y = fmaxf(fmaf(acc[5], sc, b1.y), 0.f);
    o1.z = fmaxf(fmaf(acc[6], sc, b1.z), 0.f);
    o1.w = fmaxf(fmaf(acc[7], sc, b1.w), 0.f);
    float* dst = &out[(size_t)c * D_OUT + colb];
    *(float4*)dst       = o0;
    *(float4*)(dst + 4) = o1;
}

extern "C" void kernel_launch(void* const* d_in, const int* in_sizes, int n_in,
                              void* d_out, int out_size, void* d_ws, size_t ws_size,
                              hipStream_t stream) {
    const float* x   = (const float*)d_in[0];
    const int*   ei  = (const int*)d_in[1];
    const float* W   = (const float*)d_in[2];
    const float* b   = (const float*)d_in[3];
    float*       out = (float*)d_out;

    const int* row = ei;
    const int* col = ei + N_EDGES;

    char* p = (char*)d_ws;
    unsigned short* yb = (unsigned short*)p;  p += (size_t)N_NODES * D_OUT * 2;   // 25.6 MB
    unsigned short* Wt = (unsigned short*)p;  p += (size_t)D_OUT * D_IN * 2;      // 256 KB
    int*   csr_src = (int*)p;                 p += (size_t)N_EDGES * 4;           // 3.2 MB
    int*   cnt4    = (int*)p;                 p += (size_t)4 * N_NODES * 4;       // 800 KB
    int*   row_ptr = (int*)p;                 p += (size_t)(N_NODES + 4) * 4;
    int*   cursor4 = (int*)p;                 p += (size_t)4 * N_NODES * 4;       // 800 KB
    float* dinv    = (float*)p;               p += (size_t)N_NODES * 4;
    int*   bsum    = (int*)p;                 p += (size_t)NBLK_SCAN * 4;

    k_wt   <<<D_IN, D_OUT, 0, stream>>>(W, Wt, cnt4);   // also zeroes cnt4
    k_count<<<(N_EDGES / 2 + 255) / 256, 256, 0, stream>>>(col, cnt4);
    k_scan1<<<NBLK_SCAN, 256, 0, stream>>>(cnt4, bsum);
    k_scan3<<<NBLK_SCAN, 256, 0, stream>>>(cnt4, bsum, row_ptr, dinv, cursor4);
    k_fill <<<(N_EDGES / 2 + 255) / 256, 256, 0, stream>>>(row, col, cursor4, csr_src);

    k_gemm<<<GEMM_NWG, 256, 0, stream>>>(x, Wt, dinv, yb);

    k_gather<<<GATH_CHUNKS * 8, 256, 0, stream>>>(row_ptr, csr_src, yb, dinv, b, out);
}

// Round 21
// 187.709 us; speedup vs baseline: 1.4033x; 1.4033x over previous
//
#include <hip/hip_runtime.h>
#include <hip/hip_bf16.h>

#define N_NODES 50000
#define N_EDGES 800000
#define D_IN    512
#define D_OUT   256
#define NBLK_SCAN ((N_NODES + 1023) / 1024)   // 49
#define GEMM_NWG (((N_NODES + 127) / 128) * 2)  // 782
#define GEMM_Q   (GEMM_NWG / 8)                  // 97
#define GEMM_R   (GEMM_NWG % 8)                  // 6
#define FILL_NB  260                             // fill role blocks in fused launch
#define FUSE_NB  (GEMM_NWG + FILL_NB)            // 1042
#define GATH_CHUNKS ((N_NODES + 63) / 64)        // 782

typedef short s8v  __attribute__((ext_vector_type(8)));
typedef float f32x4 __attribute__((ext_vector_type(4)));

__device__ __forceinline__ unsigned short bf16b(float f) {
    __hip_bfloat16 h = __float2bfloat16(f);
    return *reinterpret_cast<unsigned short*>(&h);
}
__device__ __forceinline__ float bflo(unsigned u) { return __uint_as_float(u << 16); }
__device__ __forceinline__ float bfhi(unsigned u) { return __uint_as_float(u & 0xffff0000u); }

// global -> LDS direct copy, 16B per lane; LDS dest arg = wave-uniform base,
// HW adds lane*16.
#define GLD16(gp, lp)                                                           \
    __builtin_amdgcn_global_load_lds(                                           \
        (const __attribute__((address_space(1))) unsigned int*)(const void*)(gp),\
        (__attribute__((address_space(3))) unsigned int*)(void*)(lp), 16, 0, 0)

__device__ __forceinline__ int wave_incl_scan(int v, int lane) {
    #pragma unroll
    for (int d = 1; d < 64; d <<= 1) {
        int u = __shfl_up(v, d, 64);
        if (lane >= d) v += u;
    }
    return v;
}

// ============ W transpose + bf16 convert; also zeroes cnt4 (saves a memset) ===
__global__ void k_wt(const float* __restrict__ W, unsigned short* __restrict__ Wt,
                     int* __restrict__ cnt4) {
    int k = blockIdx.x;      // 512
    int n = threadIdx.x;     // 256
    Wt[(size_t)n * D_IN + k] = bf16b(W[(size_t)k * D_OUT + n]);
    int t = (blockIdx.x * 256 + threadIdx.x) * 2;     // 262144 slots >= 200000
    if (t < 4 * N_NODES) {
        cnt4[t] = 0;
        if (t + 1 < 4 * N_NODES) cnt4[t + 1] = 0;
    }
}

// ============ CSR build (4-way replicated counters) ============

__global__ void k_count(const int* __restrict__ col, int* __restrict__ cnt4) {
    int i = (blockIdx.x * 256 + threadIdx.x) * 2;
    if (i < N_EDGES) {                            // N_EDGES even; i even
        int2 c = *(const int2*)&col[i];
        atomicAdd(&cnt4[(i & 3) * N_NODES + c.x], 1);
        atomicAdd(&cnt4[((i + 1) & 3) * N_NODES + c.y], 1);
    }
}

__launch_bounds__(256)
__global__ void k_scan1(const int* __restrict__ cnt4, int* __restrict__ bsum) {
    const int t = threadIdx.x, b = blockIdx.x;
    const int idx = b * 1024 + t * 4;
    int s = 0;
    if (idx < N_NODES) {
        #pragma unroll
        for (int q = 0; q < 4; ++q) {
            int4 v = *(const int4*)&cnt4[q * N_NODES + idx];
            s += (v.x + v.y) + (v.z + v.w);
        }
    }
    #pragma unroll
    for (int d = 1; d < 64; d <<= 1) s += __shfl_xor(s, d, 64);
    __shared__ int ws[4];
    if ((t & 63) == 0) ws[t >> 6] = s;
    __syncthreads();
    if (t == 0) bsum[b] = ws[0] + ws[1] + ws[2] + ws[3];
}

// in-block exclusive scan + self-computed block offset; emits row_ptr, dinv,
// and EXACT per-replica cursor bases cursor4[q*N+c] = row_ptr[c]+prefix_q
__launch_bounds__(256)
__global__ void k_scan3(const int* __restrict__ cnt4, const int* __restrict__ bsum,
                        int* __restrict__ row_ptr, float* __restrict__ dinv,
                        int* __restrict__ cursor4) {
    const int t = threadIdx.x, b = blockIdx.x;
    const int lane = t & 63, wv = t >> 6;
    const int idx = b * 1024 + t * 4;
    int4 vq[4];
    int4 tot = make_int4(0, 0, 0, 0);
    if (idx < N_NODES) {
        #pragma unroll
        for (int q = 0; q < 4; ++q) {
            vq[q] = *(const int4*)&cnt4[q * N_NODES + idx];
            tot.x += vq[q].x; tot.y += vq[q].y;
            tot.z += vq[q].z; tot.w += vq[q].w;
        }
    } else {
        #pragma unroll
        for (int q = 0; q < 4; ++q) vq[q] = make_int4(0, 0, 0, 0);
    }
    int s = (tot.x + tot.y) + (tot.z + tot.w);
    int isc = wave_incl_scan(s, lane);
    __shared__ int wsum[4];
    __shared__ int s_boff;
    if (lane == 63) wsum[wv] = isc;
    if (t < 64) {                                  // wave 0: sum of bsum[0..b)
        int u = (t < b) ? bsum[t] : 0;             // b <= 48 < 64
        #pragma unroll
        for (int d = 1; d < 64; d <<= 1) u += __shfl_xor(u, d, 64);
        if (t == 0) s_boff = u;
    }
    __syncthreads();
    int off = s_boff;
    #pragma unroll
    for (int i = 0; i < 4; ++i)
        if (i < wv) off += wsum[i];
    int p0 = off + isc - s;
    int p1 = p0 + tot.x;
    int p2 = p1 + tot.y;
    int p3 = p2 + tot.z;
    if (idx < N_NODES) {
        row_ptr[idx + 0] = p0; dinv[idx + 0] = rsqrtf(1.f + (float)tot.x);
        row_ptr[idx + 1] = p1; dinv[idx + 1] = rsqrtf(1.f + (float)tot.y);
        row_ptr[idx + 2] = p2; dinv[idx + 2] = rsqrtf(1.f + (float)tot.z);
        row_ptr[idx + 3] = p3; dinv[idx + 3] = rsqrtf(1.f + (float)tot.w);
        int4 run = make_int4(p0, p1, p2, p3);
        #pragma unroll
        for (int q = 0; q < 4; ++q) {
            *(int4*)&cursor4[q * N_NODES + idx] = run;
            run.x += vq[q].x; run.y += vq[q].y;
            run.z += vq[q].z; run.w += vq[q].w;
        }
    }
    if (b == 0 && t == 0) row_ptr[N_NODES] = N_EDGES;
}

// ============ FUSED: MFMA GEMM (R16 structure, bench-best) + CSR fill =========
// bid%4==3 -> fill role (260 blocks, grid-stride over edges); else gemm role
// (gid = bid - bid/4, 0..781). Fill is atomic-latency-bound, gemm stall-bound:
// co-resident blocks interleave on the CU so fill's ~25us hides under gemm.
// Correctness independent of dispatch order (fill only needs scan3 output).
__launch_bounds__(256)
__global__ void k_gemm(const float* __restrict__ A,            // [N_NODES,512] fp32
                       const unsigned short* __restrict__ Wt,  // [256,512] bf16
                       const float* __restrict__ dinv,
                       unsigned short* __restrict__ yb,        // [8][N_NODES][32] bf16
                       const int* __restrict__ row, const int* __restrict__ col,
                       int* __restrict__ cursor4, int* __restrict__ csr_src)
{
    __shared__ __align__(16) float          As[128 * 64];   // 32 KB, [m][64k] fp32
    __shared__ __align__(16) unsigned short Bs[128 * 64];   // 16 KB, [n][64k] bf16

    const int bid = blockIdx.x;
    const int t   = threadIdx.x;

    if ((bid & 3) == 3) {                      // ---- fill role ----
        const int cid = bid >> 2;              // 0..259
        const int stride = FILL_NB * 256 * 2;
        for (int i = (cid * 256 + t) * 2; i < N_EDGES; i += stride) {
            int2 c = *(const int2*)&col[i];
            int2 r = *(const int2*)&row[i];
            int p0 = atomicAdd(&cursor4[(i & 3) * N_NODES + c.x], 1);
            csr_src[p0] = r.x;
            int p1 = atomicAdd(&cursor4[((i + 1) & 3) * N_NODES + c.y], 1);
            csr_src[p1] = r.y;
        }
        return;
    }

    const int gid = bid - (bid >> 2);          // 0..781

    // bijective XCD swizzle (m204) on gid
    int xcd = gid % 8, pos = gid / 8;
    int wg = (xcd < GEMM_R) ? xcd * (GEMM_Q + 1) + pos
                            : GEMM_R * (GEMM_Q + 1) + (xcd - GEMM_R) * GEMM_Q + pos;
    const int nt = wg & 1;
    const int mt = wg >> 1;
    const int m0 = mt * 128;
    const int n0 = nt * 128;

    const int w  = t >> 6;
    const int l  = t & 63;
    const int wm = (w >> 1) * 64;
    const int wn = (w & 1) * 64;
    const int lr = l & 15;
    const int lk = l >> 4;

    // A staging: lane l -> LDS row rowbase+(l>>4), dest 16B-slot l&15;
    // source 16B-slot = (l&15) ^ (row&7)
    size_t aoff[8];
    #pragma unroll
    for (int i = 0; i < 8; ++i) {
        int rw = m0 + w * 32 + i * 4 + (l >> 4);
        if (rw >= N_NODES) rw = 0;             // tail clamp; outputs guarded
        int sslot = (l & 15) ^ (rw & 7);
        aoff[i] = (size_t)rw * D_IN + sslot * 4;   // float units
    }
    // B staging (bf16, 16B-chunk swizzle, zero-conflict since R7)
    const int srow = l >> 3;
    const int srcj = (l & 7) ^ srow;
    size_t boff[4];
    #pragma unroll
    for (int i = 0; i < 4; ++i) {
        int g = w * 4 + i;
        int bn = n0 + g * 8 + srow;
        boff[i] = (size_t)bn * D_IN + srcj * 8;
    }

    f32x4 acc[4][4] = {};

    for (int kk = 0; kk < D_IN; kk += 64) {
        #pragma unroll
        for (int i = 0; i < 8; ++i)
            GLD16(&A[aoff[i] + kk], (char*)As + (w * 32 + i * 4) * 256);
        #pragma unroll
        for (int i = 0; i < 4; ++i)
            GLD16(&Wt[boff[i] + kk], (char*)Bs + (w * 4 + i) * 1024);
        __syncthreads();

        #pragma unroll
        for (int ks = 0; ks < 2; ++ks) {
            s8v af[4], bfr[4];
            #pragma unroll
            for (int f = 0; f < 4; ++f) {
                int rw = wm + f * 16 + lr;            // row&7 == lr&7
                int a  = (ks * 4 + lk) * 2;           // logical 16B slot (even)
                int s0 = a ^ (lr & 7);
                int s1 = (a + 1) ^ (lr & 7);          // = s0 ^ 1
                const char* pr = (const char*)As + rw * 256;
                float4 x0 = *(const float4*)(pr + s0 * 16);
                float4 x1 = *(const float4*)(pr + s1 * 16);
                union { s8v v; unsigned short h[8]; } u;
                u.h[0] = bf16b(x0.x); u.h[1] = bf16b(x0.y);
                u.h[2] = bf16b(x0.z); u.h[3] = bf16b(x0.w);
                u.h[4] = bf16b(x1.x); u.h[5] = bf16b(x1.y);
                u.h[6] = bf16b(x1.z); u.h[7] = bf16b(x1.w);
                af[f] = u.v;
            }
            const int kb = (ks * 64 + lk * 16) ^ ((lr & 7) << 4);
            #pragma unroll
            for (int f = 0; f < 4; ++f)
                bfr[f] = *(const s8v*)((const char*)Bs + ((wn + f * 16 + lr) * 128 + kb));
            #pragma unroll
            for (int fm = 0; fm < 4; ++fm)
                #pragma unroll
                for (int fn = 0; fn < 4; ++fn)
                    acc[fm][fn] = __builtin_amdgcn_mfma_f32_16x16x32_bf16(
                        af[fm], bfr[fn], acc[fm][fn], 0, 0, 0);
        }
        __syncthreads();
    }

    #pragma unroll
    for (int fm = 0; fm < 4; ++fm) {
        #pragma unroll
        for (int j = 0; j < 4; ++j) {
            int rw = m0 + wm + fm * 16 + lk * 4 + j;
            if (rw < N_NODES) {
                float s = dinv[rw];
                #pragma unroll
                for (int fn = 0; fn < 4; ++fn) {
                    int cl = n0 + wn + fn * 16 + lr;
                    size_t off = (size_t)(cl >> 5) * (N_NODES * 32)
                               + (size_t)rw * 32 + (cl & 31);
                    yb[off] = bf16b(acc[fm][fn][j] * s);
                }
            }
        }
    }
}

// ============ gather (column-partitioned, rounds of 8) ============
// R16 structure (bench-best: slice=bid%8 keeps each XCD in its 3.2MB
// L2-resident column slice; 4-lane groups, group = one target, lane = one
// 16B col-slot, no cross-lane reduction). Single change vs R16: rounds of
// 4 -> 8 edges in flight (latency legs per node halve; clamped slots re-hit
// the same L1 line so byte cost is small).
__device__ __forceinline__ void add8(float* acc, uint4 q) {
    unsigned x;
    x = q.x; acc[0] += bflo(x); acc[1] += bfhi(x);
    x = q.y; acc[2] += bflo(x); acc[3] += bfhi(x);
    x = q.z; acc[4] += bflo(x); acc[5] += bfhi(x);
    x = q.w; acc[6] += bflo(x); acc[7] += bfhi(x);
}

__launch_bounds__(256)
__global__ void k_gather(const int* __restrict__ row_ptr, const int* __restrict__ csr_src,
                         const unsigned short* __restrict__ yb,   // [8][N_NODES][32]
                         const float* __restrict__ dinv,
                         const float* __restrict__ bias, float* __restrict__ out)
{
    const int s     = blockIdx.x & 7;          // slice -> XCD (dispatch %8)
    const int chunk = blockIdx.x >> 3;
    const int g     = threadIdx.x >> 2;        // group 0..63 = target
    const int cs    = threadIdx.x & 3;         // 16B col-slot within slice
    const int c     = chunk * 64 + g;
    if (c >= N_NODES) return;

    const uint4* t4 = (const uint4*)(yb + (size_t)s * N_NODES * 32);  // 4 uint4/node

    float acc[8] = {0.f,0.f,0.f,0.f,0.f,0.f,0.f,0.f};

    const int e0 = row_ptr[c];
    const int e1 = row_ptr[c + 1];
    for (int i = e0; i < e1; i += 8) {
        int idx[8];
        #pragma unroll
        for (int j = 0; j < 8; ++j) {
            int p = i + j;
            idx[j] = csr_src[p < e1 ? p : e1 - 1];   // clamp: L1-hot re-read
        }
        uint4 v[8];
        #pragma unroll
        for (int j = 0; j < 8; ++j) v[j] = t4[(size_t)idx[j] * 4 + cs];
        #pragma unroll
        for (int j = 0; j < 8; ++j)
            if (i + j < e1) add8(acc, v[j]);         // group-uniform predicate
    }

    add8(acc, t4[(size_t)c * 4 + cs]);               // self-loop term

    const float sc = dinv[c];
    const int colb = s * 32 + cs * 8;
    float4 b0 = *(const float4*)&bias[colb];
    float4 b1 = *(const float4*)&bias[colb + 4];
    float4 o0, o1;
    o0.x = fmaxf(fmaf(acc[0], sc, b0.x), 0.f);
    o0.y = fmaxf(fmaf(acc[1], sc, b0.y), 0.f);
    o0.z = fmaxf(fmaf(acc[2], sc, b0.z), 0.f);
    o0.w = fmaxf(fmaf(acc[3], sc, b0.w), 0.f);
    o1.x = fmaxf(fmaf(acc[4], sc, b1.x), 0.f);
    o1.y = fmaxf(fmaf(acc[5], sc, b1.y), 0.f);
    o1.z = fmaxf(fmaf(acc[6], sc, b1.z), 0.f);
    o1.w = fmaxf(fmaf(acc[7], sc, b1.w), 0.f);
    float* dst = &out[(size_t)c * D_OUT + colb];
    *(float4*)dst       = o0;
    *(float4*)(dst + 4) = o1;
}

extern "C" void kernel_launch(void* const* d_in, const int* in_sizes, int n_in,
                              void* d_out, int out_size, void* d_ws, size_t ws_size,
                              hipStream_t stream) {
    const float* x   = (const float*)d_in[0];
    const int*   ei  = (const int*)d_in[1];
    const float* W   = (const float*)d_in[2];
    const float* b   = (const float*)d_in[3];
    float*       out = (float*)d_out;

    const int* row = ei;
    const int* col = ei + N_EDGES;

    char* p = (char*)d_ws;
    unsigned short* yb = (unsigned short*)p;  p += (size_t)N_NODES * D_OUT * 2;   // 25.6 MB
    unsigned short* Wt = (unsigned short*)p;  p += (size_t)D_OUT * D_IN * 2;      // 256 KB
    int*   csr_src = (int*)p;                 p += (size_t)N_EDGES * 4;           // 3.2 MB
    int*   cnt4    = (int*)p;                 p += (size_t)4 * N_NODES * 4;       // 800 KB
    int*   row_ptr = (int*)p;                 p += (size_t)(N_NODES + 4) * 4;
    int*   cursor4 = (int*)p;                 p += (size_t)4 * N_NODES * 4;       // 800 KB
    float* dinv    = (float*)p;               p += (size_t)N_NODES * 4;
    int*   bsum    = (int*)p;                 p += (size_t)NBLK_SCAN * 4;

    k_wt   <<<D_IN, D_OUT, 0, stream>>>(W, Wt, cnt4);   // also zeroes cnt4
    k_count<<<(N_EDGES / 2 + 255) / 256, 256, 0, stream>>>(col, cnt4);
    k_scan1<<<NBLK_SCAN, 256, 0, stream>>>(cnt4, bsum);
    k_scan3<<<NBLK_SCAN, 256, 0, stream>>>(cnt4, bsum, row_ptr, dinv, cursor4);

    // fused gemm + fill (fill role blocks interleaved at bid%4==3)
    k_gemm<<<FUSE_NB, 256, 0, stream>>>(x, Wt, dinv, yb, row, col, cursor4, csr_src);

    k_gather<<<GATH_CHUNKS * 8, 256, 0, stream>>>(row_ptr, csr_src, yb, dinv, b, out);
}